// Round 10
// baseline (85.781 us; speedup 1.0000x reference)
//
#include <hip/hip_runtime.h>

#define NB 256
#define NP 512
#define NE 256
#define NH 128
#define PT 32              // pool rows per tile
#define HALF 256           // pool rows per block (P split across 2 blocks)
#define NT (HALF / PT)     // 8 tiles per block

typedef __attribute__((ext_vector_type(8))) short bf16x8;
typedef __attribute__((ext_vector_type(4))) float f32x4;

__device__ __forceinline__ short f2bf(float f) {
  union { float f; unsigned u; } v; v.f = f;
  unsigned r = v.u + 0x7fffu + ((v.u >> 16) & 1u);   // RNE
  return (short)(r >> 16);
}
__device__ __forceinline__ float bf2f(short s) {
  union { unsigned u; float f; } v;
  v.u = ((unsigned)(unsigned short)s) << 16;
  return v.f;
}
// tanh(x) = 1 - 2/(exp2(2*log2e*x)+1)
__device__ __forceinline__ float fast_tanh(float x) {
  float u = __builtin_amdgcn_exp2f(x * 2.8853900817779268f);
  return 1.0f - 2.0f * __builtin_amdgcn_rcpf(u + 1.0f);
}

// Raw barrier: waits LDS ops only — vmem loads stay IN FLIGHT across it.
#define BARRIER() do {                                        \
  asm volatile("s_waitcnt lgkmcnt(0)" ::: "memory");          \
  __builtin_amdgcn_sched_barrier(0);                          \
  __builtin_amdgcn_s_barrier();                               \
  __builtin_amdgcn_sched_barrier(0);                          \
} while (0)

// ---- prologue: w1 fp32 -> bf16 (64 KB, L2-hot for the main kernel) ----
__global__ void pathattn_w1cvt(const float* __restrict__ w1,
                               short* __restrict__ w1b) {
  const int i = blockIdx.x * 256 + threadIdx.x;
  w1b[i] = f2bf(w1[i]);
}

union SMem {
  struct {
    short buf[2][PT * NE];   // 2 x 16 KB bf16 tiles (slot-XOR-swizzled)
    float sp[PT][12];        // score partials [p][wave] (stride 48 B)
    float zsh[8];
  } s;
  float pool[16][NE];        // epilogue partials (16 KB, aliases buf[0])
};

// ---- main: 8 waves, bf16 LDS dbuf, reg-staged with counted-vmcnt pipeline ----
__global__ __launch_bounds__(512, 4) void pathattn_main(
    const float* __restrict__ x, const short* __restrict__ w1b,
    const float* __restrict__ w2, float* __restrict__ wsPool,
    float* __restrict__ wsZ) {
  __shared__ SMem sm;

  const int tid  = threadIdx.x;
  const int lane = tid & 63;
  const int wid  = tid >> 6;           // 0..7 — wave owns h-rows [16w,16w+16)
  const int n15  = lane & 15;
  const int l4   = lane >> 4;          // 0..3
  const int b    = blockIdx.x >> 1;
  const int half = blockIdx.x & 1;
  const float* xb = x + (size_t)b * NP * NE + (size_t)half * HALF * NE;

  // ---- A-fragments: wave's 16 w1-rows, bf16, L2-hot (32 VGPR) ----
  bf16x8 afrag[8];
  #pragma unroll
  for (int kt = 0; kt < 8; ++kt)
    afrag[kt] = *(const bf16x8*)(w1b + (wid * 16 + n15) * NE + kt * 32 + l4 * 8);
  const f32x4 w2v = *(const f32x4*)(w2 + wid * 16 + l4 * 4);

  // ---- staging: thread owns row srow, LDS slots s0 and s0+16 (16B each).
  // LDS slot s of row r holds global bf16-chunk s ^ (r&7) (XOR swizzle). ----
  const int srow = tid >> 4;           // 0..31
  const int s0   = tid & 15;
  f32x4 sreg[2][4];                    // two named reg-sets (static indexing)

  auto gissue = [&](int t, int rs) {   // 4 global_load_dwordx4, stay in flight
    const float* gb = xb + (size_t)t * PT * NE + (size_t)srow * NE;
    #pragma unroll
    for (int j = 0; j < 2; ++j) {
      const int gc = (s0 + j * 16) ^ (srow & 7);
      sreg[rs][j * 2]     = *(const f32x4*)(gb + gc * 8);
      sreg[rs][j * 2 + 1] = *(const f32x4*)(gb + gc * 8 + 4);
    }
  };
  auto lwrite = [&](int bi, int rs) {  // cvt + 2 ds_write_b128 (auto vmcnt(4))
    short* dst = sm.s.buf[bi] + srow * NE;
    #pragma unroll
    for (int j = 0; j < 2; ++j) {
      bf16x8 v;
      v[0] = f2bf(sreg[rs][j*2][0]);   v[1] = f2bf(sreg[rs][j*2][1]);
      v[2] = f2bf(sreg[rs][j*2][2]);   v[3] = f2bf(sreg[rs][j*2][3]);
      v[4] = f2bf(sreg[rs][j*2+1][0]); v[5] = f2bf(sreg[rs][j*2+1][1]);
      v[6] = f2bf(sreg[rs][j*2+1][2]); v[7] = f2bf(sreg[rs][j*2+1][3]);
      *(bf16x8*)(dst + (s0 + j * 16) * 8) = v;
    }
  };

  // ---- MFMA: D[h][p] = sum_k w1[h][k]*x[p][k]; wave: 16h x 32p ----
  const int key = n15 & 7;
  auto mfma_sp = [&](int bi) {
    const short* xt = sm.s.buf[bi];
    f32x4 acc0 = {0.f,0.f,0.f,0.f}, acc1 = {0.f,0.f,0.f,0.f};
    #pragma unroll
    for (int kt = 0; kt < 8; ++kt) {
      const int sl = ((kt * 4 + l4) ^ key) * 8;
      bf16x8 bv0 = *(const bf16x8*)(xt + n15 * NE + sl);
      bf16x8 bv1 = *(const bf16x8*)(xt + (16 + n15) * NE + sl);
      acc0 = __builtin_amdgcn_mfma_f32_16x16x32_bf16(afrag[kt], bv0, acc0, 0, 0, 0);
      acc1 = __builtin_amdgcn_mfma_f32_16x16x32_bf16(afrag[kt], bv1, acc1, 0, 0, 0);
    }
    // D layout: col(p)=n15, row(h)=wid*16 + l4*4 + r
    float sa = 0.f, sb = 0.f;
    #pragma unroll
    for (int r = 0; r < 4; ++r) {
      sa += fast_tanh(acc0[r]) * w2v[r];
      sb += fast_tanh(acc1[r]) * w2v[r];
    }
    sa += __shfl_xor(sa, 16, 64); sa += __shfl_xor(sa, 32, 64);
    sb += __shfl_xor(sb, 16, 64); sb += __shfl_xor(sb, 32, 64);
    if (l4 == 0) {
      sm.s.sp[n15][wid]      = sa;
      sm.s.sp[16 + n15][wid] = sb;
    }
  };

  // ---- exp + pool: (wave, lane-half) covers 4 rows; lane owns 8 e's ----
  float zacc = 0.f;
  float pacc[8] = {0.f,0.f,0.f,0.f,0.f,0.f,0.f,0.f};
  const int prA = wid * 4 + (lane >> 5);   // rows prA, prA+2
  const int ec  = lane & 31;               // e-chunk: e = ec*8 .. +7
  auto exp_pool = [&](int bi) {
    const short* xt = sm.s.buf[bi];
    #pragma unroll
    for (int j = 0; j < 2; ++j) {
      const int r = prA + j * 2;
      f32x4 u = *(const f32x4*)(&sm.s.sp[r][0]);   // broadcast reads
      f32x4 w = *(const f32x4*)(&sm.s.sp[r][4]);
      float s = (u[0]+u[1]+u[2]+u[3]) + (w[0]+w[1]+w[2]+w[3]);
      // no max-subtraction: |s| <= ||w2||_1 <= 12.8
      float e = __builtin_amdgcn_exp2f(s * 1.4426950408889634f);
      zacc += e;
      bf16x8 v = *(const bf16x8*)(xt + r * NE + ((ec ^ (r & 7)) * 8));
      #pragma unroll
      for (int i = 0; i < 8; ++i) pacc[i] += e * bf2f(v[i]);
    }
  };

  // ---- pipeline: raw barriers, loads for t+2 in flight across both ----
  gissue(0, 0);
  gissue(1, 1);
  lwrite(0, 0);                        // compiler waits vmcnt(4): G(1) flies on
  BARRIER();
  #pragma unroll
  for (int t = 0; t < NT; ++t) {
    if (t + 2 < NT) gissue(t + 2, t & 1);
    mfma_sp(t & 1);
    BARRIER();                         // B1: sp visible; vmem NOT drained
    exp_pool(t & 1);
    if (t + 1 < NT) lwrite((t + 1) & 1, (t + 1) & 1);  // auto vmcnt(4)
    BARRIER();                         // B2: next buffer staged
  }

  // ---- epilogue ----
  zacc += __shfl_xor(zacc, 32, 64);    // combine lane-halves -> wave's true Z
  if (lane == 0) sm.s.zsh[wid] = zacc;
  const int g = wid * 2 + (lane >> 5); // 16 (wave,half) groups
  f32x4 p0 = {pacc[0], pacc[1], pacc[2], pacc[3]};
  f32x4 p1 = {pacc[4], pacc[5], pacc[6], pacc[7]};
  *(f32x4*)(&sm.pool[g][ec * 8])     = p0;   // pool aliases buf[0]; all tile
  *(f32x4*)(&sm.pool[g][ec * 8 + 4]) = p1;   // reads retired at last BARRIER
  BARRIER();
  if (tid < NE) {
    float v = 0.f;
    #pragma unroll
    for (int q = 0; q < 16; ++q) v += sm.pool[q][tid];
    wsPool[(size_t)blockIdx.x * NE + tid] = v;
  }
  if (tid == 0) {
    float z = 0.f;
    #pragma unroll
    for (int w = 0; w < 8; ++w) z += sm.s.zsh[w];
    wsZ[blockIdx.x] = z;
  }
}

// ---- combine the two P-halves and normalize ----
__global__ void pathattn_combine(const float* __restrict__ wsPool,
                                 const float* __restrict__ wsZ,
                                 float* __restrict__ out) {
  const int b = blockIdx.x, e = threadIdx.x;
  float v = wsPool[(size_t)(2*b) * NE + e] + wsPool[(size_t)(2*b+1) * NE + e];
  float z = wsZ[2*b] + wsZ[2*b+1];
  out[(size_t)b * NE + e] = v / z;
}

extern "C" void kernel_launch(void* const* d_in, const int* in_sizes, int n_in,
                              void* d_out, int out_size, void* d_ws, size_t ws_size,
                              hipStream_t stream) {
  (void)in_sizes; (void)n_in; (void)out_size; (void)ws_size;
  const float* x  = (const float*)d_in[0];
  const float* w1 = (const float*)d_in[1];
  const float* w2 = (const float*)d_in[2];
  float* out = (float*)d_out;
  short* w1b    = (short*)d_ws;                    // [128*256] bf16 (64 KB)
  float* wsPool = (float*)((char*)d_ws + 65536);   // [512][256] f32
  float* wsZ    = wsPool + 512 * NE;               // [512] f32
  pathattn_w1cvt<<<NH * NE / 256, 256, 0, stream>>>(w1, w1b);
  pathattn_main<<<2 * NB, 512, 0, stream>>>(x, w1b, w2, wsPool, wsZ);
  pathattn_combine<<<NB, NE, 0, stream>>>(wsPool, wsZ, out);
}

// Round 11
// 40.148 us; speedup vs baseline: 2.1366x; 2.1366x over previous
//
#include <hip/hip_runtime.h>

#define NB 256
#define NP 512
#define NE 256
#define NH 128
#define PT 16              // pool rows per tile
#define HALF 256           // pool rows per block (P split across 2 blocks)
#define NT (HALF / PT)     // 16 tiles per block

typedef __attribute__((ext_vector_type(8))) short bf16x8;
typedef __attribute__((ext_vector_type(4))) float f32x4;

__device__ __forceinline__ short f2bf(float f) {
  union { float f; unsigned u; } v; v.f = f;
  unsigned r = v.u + 0x7fffu + ((v.u >> 16) & 1u);   // RNE
  return (short)(r >> 16);
}
__device__ __forceinline__ float bf2f(short s) {
  union { unsigned u; float f; } v;
  v.u = ((unsigned)(unsigned short)s) << 16;
  return v.f;
}
// tanh(x) = 1 - 2/(exp2(2*log2e*x)+1)
__device__ __forceinline__ float fast_tanh(float x) {
  float u = __builtin_amdgcn_exp2f(x * 2.8853900817779268f);
  return 1.0f - 2.0f * __builtin_amdgcn_rcpf(u + 1.0f);
}

// LDS-only barrier: vmem (global_load_lds) stays IN FLIGHT across it.
#define LBAR() do {                                           \
  asm volatile("s_waitcnt lgkmcnt(0)" ::: "memory");          \
  __builtin_amdgcn_sched_barrier(0);                          \
  __builtin_amdgcn_s_barrier();                               \
  __builtin_amdgcn_sched_barrier(0);                          \
} while (0)
#define VWAIT2() do {                                         \
  asm volatile("s_waitcnt vmcnt(2)" ::: "memory");            \
  __builtin_amdgcn_sched_barrier(0);                          \
} while (0)
#define VWAIT0() do {                                         \
  asm volatile("s_waitcnt vmcnt(0)" ::: "memory");            \
  __builtin_amdgcn_sched_barrier(0);                          \
} while (0)

// ---- prologue: w1 fp32 -> bf16 (64 KB, L2-hot for the main kernel) ----
__global__ void pathattn_w1cvt(const float* __restrict__ w1,
                               short* __restrict__ w1b) {
  const int i = blockIdx.x * 256 + threadIdx.x;
  w1b[i] = f2bf(w1[i]);
}

union SMem {
  struct {
    float fbuf[2][PT * NE];   // fp32 stage tiles, 32 KB (gload_lds dst, linear)
    short bbuf[2][PT * NE];   // bf16 tiles, 16 KB (swizzle carried from fbuf)
    float sp[PT][12];         // score partials [p][wave]
    float zsh[8];
  } s;
  float pool[16][NE];         // epilogue partials (16 KB, aliases fbuf[0])
};

// ---- main: 8 waves; gload_lds staging (no staging VGPRs), in-LDS cvt pass,
// counted vmcnt(2) across raw barriers (tile t+2 always in flight). ----
__global__ __launch_bounds__(512, 4) void pathattn_main(
    const float* __restrict__ x, const short* __restrict__ w1b,
    const float* __restrict__ w2, float* __restrict__ wsPool,
    float* __restrict__ wsZ) {
  __shared__ SMem sm;

  const int tid  = threadIdx.x;
  const int lane = tid & 63;
  const int wid  = tid >> 6;           // 0..7 — wave owns h-rows [16w,16w+16)
  const int n15  = lane & 15;
  const int l4   = lane >> 4;          // 0..3
  const int b    = blockIdx.x >> 1;
  const int half = blockIdx.x & 1;
  const float* xb = x + (size_t)b * NP * NE + (size_t)half * HALF * NE;

  // ---- A-fragments: wave's 16 w1-rows, bf16, L2-hot (32 VGPR) ----
  bf16x8 afrag[8];
  #pragma unroll
  for (int kt = 0; kt < 8; ++kt)
    afrag[kt] = *(const bf16x8*)(w1b + (wid * 16 + n15) * NE + kt * 32 + l4 * 8);
  const f32x4 w2v = *(const f32x4*)(w2 + wid * 16 + l4 * 4);

  // ---- staging: global_load_lds, LDS linear, swizzle on the GLOBAL address.
  // 32B-granule g of row r in LDS holds global granule g ^ (r&7). ----
  const int gq = ((lane >> 1) & 31);   // lane's 32B granule, half = lane&1
  auto gissue = [&](int t) {
    float* dstb = sm.s.fbuf[t & 1];
    const float* gb = xb + (size_t)t * PT * NE;
    #pragma unroll
    for (int j = 0; j < 2; ++j) {
      const int r = wid * 2 + j;
      const float* g = gb + (size_t)r * NE + ((gq ^ (r & 7)) * 8 + (lane & 1) * 4);
      __builtin_amdgcn_global_load_lds(
          (const __attribute__((address_space(1))) unsigned int*)g,
          (__attribute__((address_space(3))) unsigned int*)(dstb + r * NE),
          16, 0, 0);
    }
  };

  // ---- cvt pass: fbuf -> bbuf once per tile (position-preserving) ----
  const int cr = tid >> 5;             // 0..15 row
  const int cq = tid & 31;             // 32B granule
  auto cvt = [&](int t) {
    const float* fr = sm.s.fbuf[t & 1] + cr * NE + cq * 8;
    f32x4 a = *(const f32x4*)fr;
    f32x4 c = *(const f32x4*)(fr + 4);
    bf16x8 v;
    v[0]=f2bf(a[0]); v[1]=f2bf(a[1]); v[2]=f2bf(a[2]); v[3]=f2bf(a[3]);
    v[4]=f2bf(c[0]); v[5]=f2bf(c[1]); v[6]=f2bf(c[2]); v[7]=f2bf(c[3]);
    *(bf16x8*)(sm.s.bbuf[t & 1] + cr * NE + cq * 8) = v;
  };

  // ---- MFMA: D[h][p] = sum_k w1[h][k]*x[p][k]; wave: 16h x 16p ----
  auto mfma_sp = [&](int t) {
    const short* xt = sm.s.bbuf[t & 1];
    f32x4 acc = {0.f, 0.f, 0.f, 0.f};
    #pragma unroll
    for (int kt = 0; kt < 8; ++kt) {
      bf16x8 bv = *(const bf16x8*)(xt + n15 * NE + (((kt * 4 + l4) ^ (n15 & 7)) * 8));
      acc = __builtin_amdgcn_mfma_f32_16x16x32_bf16(afrag[kt], bv, acc, 0, 0, 0);
    }
    // D layout: col(p)=n15, row(h)=wid*16 + l4*4 + r
    float s = 0.f;
    #pragma unroll
    for (int r = 0; r < 4; ++r) s += fast_tanh(acc[r]) * w2v[r];
    s += __shfl_xor(s, 16, 64);
    s += __shfl_xor(s, 32, 64);
    if (l4 == 0) sm.s.sp[n15][wid] = s;
  };

  // ---- exp + pool: (wave, lane-half) owns 1 row; lane owns 8 e's ----
  float zacc = 0.f;
  float pacc[8] = {0.f,0.f,0.f,0.f,0.f,0.f,0.f,0.f};
  const int pr_ = wid * 2 + (lane >> 5);   // this half's row
  const int ec  = lane & 31;               // e-chunk: e = ec*8 .. +7
  auto exp_pool = [&](int t) {
    const short* xt = sm.s.bbuf[t & 1];
    f32x4 u = *(const f32x4*)(&sm.s.sp[pr_][0]);   // broadcast reads
    f32x4 w = *(const f32x4*)(&sm.s.sp[pr_][4]);
    float s = (u[0]+u[1]+u[2]+u[3]) + (w[0]+w[1]+w[2]+w[3]);
    // no max-subtraction: |s| <= ||w2||_1 <= 12.8
    float e = __builtin_amdgcn_exp2f(s * 1.4426950408889634f);
    zacc += e;                               // 32x replicated per row
    bf16x8 v = *(const bf16x8*)(xt + pr_ * NE + ((ec ^ (pr_ & 7)) * 8));
    #pragma unroll
    for (int i = 0; i < 8; ++i) pacc[i] += e * bf2f(v[i]);
  };

  // ---- pipeline ----
  gissue(0);
  gissue(1);
  VWAIT2();                    // tile 0 landed; tile 1 still flying
  LBAR();
  cvt(0);
  LBAR();
  #pragma unroll 1
  for (int t = 0; t < NT; ++t) {
    if (t + 2 < NT) gissue(t + 2);        // 2 loads join the queue
    mfma_sp(t);
    if (t + 2 < NT)      VWAIT2();        // tile t+1 landed; t+2 flying
    else if (t + 1 < NT) VWAIT0();        // last fill: drain
    LBAR();                               // sp visible + fbuf(t+1) safe for all
    exp_pool(t);
    if (t + 1 < NT) cvt(t + 1);
    LBAR();                               // bbuf(t+1) ready; bbuf(t) reads done
  }

  // ---- epilogue (pool aliases fbuf[0]; all fbuf/bbuf traffic retired) ----
  #pragma unroll
  for (int m = 1; m <= 32; m <<= 1) zacc += __shfl_xor(zacc, m, 64);
  if (lane == 0) sm.s.zsh[wid] = zacc * 0.03125f;   // /32 lane replication
  const int g = wid * 2 + (lane >> 5);
  f32x4 p0 = {pacc[0], pacc[1], pacc[2], pacc[3]};
  f32x4 p1 = {pacc[4], pacc[5], pacc[6], pacc[7]};
  *(f32x4*)(&sm.pool[g][ec * 8])     = p0;
  *(f32x4*)(&sm.pool[g][ec * 8 + 4]) = p1;
  LBAR();
  if (tid < NE) {
    float v = 0.f;
    #pragma unroll
    for (int q = 0; q < 16; ++q) v += sm.pool[q][tid];
    wsPool[(size_t)blockIdx.x * NE + tid] = v;
  }
  if (tid == 0) {
    float z = 0.f;
    #pragma unroll
    for (int w = 0; w < 8; ++w) z += sm.s.zsh[w];
    wsZ[blockIdx.x] = z;
  }
}

// ---- combine the two P-halves and normalize ----
__global__ void pathattn_combine(const float* __restrict__ wsPool,
                                 const float* __restrict__ wsZ,
                                 float* __restrict__ out) {
  const int b = blockIdx.x, e = threadIdx.x;
  float v = wsPool[(size_t)(2*b) * NE + e] + wsPool[(size_t)(2*b+1) * NE + e];
  float z = wsZ[2*b] + wsZ[2*b+1];
  out[(size_t)b * NE + e] = v / z;
}

extern "C" void kernel_launch(void* const* d_in, const int* in_sizes, int n_in,
                              void* d_out, int out_size, void* d_ws, size_t ws_size,
                              hipStream_t stream) {
  (void)in_sizes; (void)n_in; (void)out_size; (void)ws_size;
  const float* x  = (const float*)d_in[0];
  const float* w1 = (const float*)d_in[1];
  const float* w2 = (const float*)d_in[2];
  float* out = (float*)d_out;
  short* w1b    = (short*)d_ws;                    // [128*256] bf16 (64 KB)
  float* wsPool = (float*)((char*)d_ws + 65536);   // [512][256] f32
  float* wsZ    = wsPool + 512 * NE;               // [512] f32
  pathattn_w1cvt<<<NH * NE / 256, 256, 0, stream>>>(w1, w1b);
  pathattn_main<<<2 * NB, 512, 0, stream>>>(x, w1b, w2, wsPool, wsZ);
  pathattn_combine<<<NB, NE, 0, stream>>>(wsPool, wsZ, out);
}